// Round 1
// baseline (606.217 us; speedup 1.0000x reference)
//
#include <hip/hip_runtime.h>
#include <hip/hip_bf16.h>

#define CDIM 384
#define NQKV 1152
#define HEADS 12
#define NTOK 64
#define MTOT 131072
#define NCHUNK 4
#define MCHUNK 32768     // rows per chunk (8 images)
#define WINCHUNK 512     // windows per chunk
#define SHIFT_ 4
#define SCALE_Q 0.17677669529663687f  // 32^-0.5

typedef __attribute__((ext_vector_type(8))) short bf16x8;
typedef __attribute__((ext_vector_type(4))) float f32x4;
typedef __attribute__((ext_vector_type(4))) float float4_t;

__device__ inline short f2bf(float f) {
    union { float f; unsigned u; } v; v.f = f;
    unsigned r = v.u + 0x7FFFu + ((v.u >> 16) & 1u);
    return (short)(r >> 16);
}

// ---------------- prep: weight transpose->bf16, bias matrix ----------------
__global__ void prep_kernel(const float* __restrict__ qkv_w,
                            const float* __restrict__ proj_w,
                            const float* __restrict__ bias_table,
                            const int* __restrict__ rel_index,
                            short* __restrict__ qkvwt,
                            short* __restrict__ projwt,
                            float* __restrict__ biasmat) {
    int t = blockIdx.x * 256 + threadIdx.x;
    if (t < NQKV * CDIM) {             // qkvwt[n][k] = qkv_w[k][n]
        int n = t / CDIM, k = t - n * CDIM;
        qkvwt[t] = f2bf(qkv_w[k * NQKV + n]);
    }
    if (t < CDIM * CDIM) {             // projwt[n][k] = proj_w[k][n]
        int n = t / CDIM, k = t - n * CDIM;
        projwt[t] = f2bf(proj_w[k * CDIM + n]);
    }
    if (t < HEADS * NTOK * NTOK) {     // biasmat[h][i][j]
        int h = t >> 12, ij = t & 4095;
        biasmat[t] = bias_table[rel_index[ij] * HEADS + h];
    }
}

// ---------------- GEMM1: qkv = window(x) @ qkv_w + b  (bf16 out) -----------
// 128x128 tile, BK=32, 4 waves (2x2), each wave 64x64 (4x4 16x16x32 frags).
// A rows are window-space rows; shift+partition folded into source address.
__global__ __launch_bounds__(256) void gemm_qkv(
    const float* __restrict__ x, const short* __restrict__ wt,
    const float* __restrict__ qkv_b, short* __restrict__ qkv, int chunk)
{
    __shared__ alignas(16) short Ab[128 * 40];
    __shared__ alignas(16) short Bb[128 * 40];
    int tid = threadIdx.x;
    int bm = blockIdx.x, bn = blockIdx.y;
    int rA = tid >> 1, half = tid & 1;
    int mloc = bm * 128 + rA;
    int mg = chunk * MCHUNK + mloc;            // global window-space row
    int win = mg >> 6, tok = mg & 63;
    int b = win >> 6, wIdx = win & 63;
    int gh = ((wIdx >> 3) << 3) + (tok >> 3);
    int gw = (wIdx & 7) * 8 + (tok & 7);
    int sh_ = (gh + SHIFT_) & 63, sw_ = (gw + SHIFT_) & 63;
    const float* xsrc = x + (size_t)(b * 4096 + sh_ * 64 + sw_) * CDIM + half * 16;
    const short* bsrc = wt + (size_t)(bn * 128 + rA) * CDIM + half * 16;
    short* aw  = &Ab[rA * 40 + half * 16];
    short* bw_ = &Bb[rA * 40 + half * 16];

    int lane = tid & 63, wv = tid >> 6;
    int wr = wv >> 1, wc = wv & 1;
    int lrow = lane & 15, lhi = lane >> 4;
    const short* ard = &Ab[(wr * 64 + lrow) * 40 + lhi * 8];
    const short* brd = &Bb[(wc * 64 + lrow) * 40 + lhi * 8];

    f32x4 zero = {0.f, 0.f, 0.f, 0.f};
    f32x4 acc[4][4];
    #pragma unroll
    for (int i = 0; i < 4; i++)
        #pragma unroll
        for (int j = 0; j < 4; j++) acc[i][j] = zero;

    for (int k0 = 0; k0 < CDIM; k0 += 32) {
        float4_t a0 = *(const float4_t*)(xsrc + k0);
        float4_t a1 = *(const float4_t*)(xsrc + k0 + 4);
        float4_t a2 = *(const float4_t*)(xsrc + k0 + 8);
        float4_t a3 = *(const float4_t*)(xsrc + k0 + 12);
        bf16x8 b0 = *(const bf16x8*)(bsrc + k0);
        bf16x8 b1 = *(const bf16x8*)(bsrc + k0 + 8);
        __syncthreads();                       // prev reads done
        bf16x8 w0, w1;
        #pragma unroll
        for (int i = 0; i < 4; i++) {
            w0[i] = f2bf(a0[i]); w0[4 + i] = f2bf(a1[i]);
            w1[i] = f2bf(a2[i]); w1[4 + i] = f2bf(a3[i]);
        }
        *(bf16x8*)aw = w0; *(bf16x8*)(aw + 8) = w1;
        *(bf16x8*)bw_ = b0; *(bf16x8*)(bw_ + 8) = b1;
        __syncthreads();
        bf16x8 af[4], bfr[4];
        #pragma unroll
        for (int t = 0; t < 4; t++) af[t]  = *(const bf16x8*)(ard + t * 16 * 40);
        #pragma unroll
        for (int t = 0; t < 4; t++) bfr[t] = *(const bf16x8*)(brd + t * 16 * 40);
        #pragma unroll
        for (int i = 0; i < 4; i++)
            #pragma unroll
            for (int j = 0; j < 4; j++)
                acc[i][j] = __builtin_amdgcn_mfma_f32_16x16x32_bf16(af[i], bfr[j], acc[i][j], 0, 0, 0);
    }
    // epilogue: +bias, pre-scale q columns, bf16 store (chunk-local rows)
    #pragma unroll
    for (int tj = 0; tj < 4; tj++) {
        int col = bn * 128 + wc * 64 + tj * 16 + lrow;
        float bias = qkv_b[col];
        float sc = (col < CDIM) ? SCALE_Q : 1.0f;
        #pragma unroll
        for (int ti = 0; ti < 4; ti++) {
            int row0 = bm * 128 + wr * 64 + ti * 16 + lhi * 4;
            #pragma unroll
            for (int r = 0; r < 4; r++) {
                float v = (acc[ti][tj][r] + bias) * sc;
                qkv[(size_t)(row0 + r) * NQKV + col] = f2bf(v);
            }
        }
    }
}

// ---------------- attention: one block per window, wave = 3 heads ----------
__global__ __launch_bounds__(256) void attn_win(
    const short* __restrict__ qkv, const float* __restrict__ biasmat,
    short* __restrict__ attno, int chunk)
{
    __shared__ alignas(16) short pbuf[4][64 * 72];
    __shared__ alignas(16) short vtb_s[4][32 * 72];
    __shared__ int regbuf[64];
    int tid = threadIdx.x;
    int wc = blockIdx.x;
    int gwin = chunk * WINCHUNK + wc;
    int wIdx = gwin & 63;
    if (tid < 64) {      // shift-mask region id per token
        int th = tid >> 3, tw = tid & 7;
        int gh = ((wIdx >> 3) << 3) + th;
        int gw = (wIdx & 7) * 8 + tw;
        int rh = gh < 56 ? 0 : (gh < 60 ? 1 : 2);
        int rw = gw < 56 ? 0 : (gw < 60 ? 1 : 2);
        regbuf[tid] = rh * 3 + rw;
    }
    __syncthreads();
    int lane = tid & 63, wv = tid >> 6;
    int lrow = lane & 15, lhi = lane >> 4;
    short* pb  = pbuf[wv];
    short* vtb = vtb_s[wv];
    const short* qb = qkv + (size_t)(wc * 64) * NQKV;   // chunk-local rows
    f32x4 zero = {0.f, 0.f, 0.f, 0.f};

    int regj[4];
    #pragma unroll
    for (int tj = 0; tj < 4; tj++) regj[tj] = regbuf[tj * 16 + lrow];

    for (int hi = 0; hi < 3; hi++) {
        int h = wv * 3 + hi;
        // V rows (token = lane), 32 dims
        const short* vsrc = qb + (size_t)lane * NQKV + 2 * CDIM + h * 32;
        bf16x8 vr0 = *(const bf16x8*)(vsrc);
        bf16x8 vr1 = *(const bf16x8*)(vsrc + 8);
        bf16x8 vr2 = *(const bf16x8*)(vsrc + 16);
        bf16x8 vr3 = *(const bf16x8*)(vsrc + 24);
        // Q/K fragments (q pre-scaled in GEMM1)
        bf16x8 qf[4], kf[4];
        #pragma unroll
        for (int t = 0; t < 4; t++) {
            qf[t] = *(const bf16x8*)(qb + (size_t)(t * 16 + lrow) * NQKV + h * 32 + lhi * 8);
            kf[t] = *(const bf16x8*)(qb + (size_t)(t * 16 + lrow) * NQKV + CDIM + h * 32 + lhi * 8);
        }
        f32x4 s[4][4];
        #pragma unroll
        for (int i = 0; i < 4; i++)
            #pragma unroll
            for (int j = 0; j < 4; j++)
                s[i][j] = __builtin_amdgcn_mfma_f32_16x16x32_bf16(qf[i], kf[j], zero, 0, 0, 0);
        // stage V^T in LDS (pad 64->72 tokens: conflict-free b128 reads)
        #pragma unroll
        for (int d = 0; d < 8; d++) {
            vtb[d * 72 + lane]        = vr0[d];
            vtb[(d + 8) * 72 + lane]  = vr1[d];
            vtb[(d + 16) * 72 + lane] = vr2[d];
            vtb[(d + 24) * 72 + lane] = vr3[d];
        }
        // softmax (rows split: 16 lanes x 4 tj hold one row)
        float rcpv[4][4];
        #pragma unroll
        for (int ti = 0; ti < 4; ti++) {
            #pragma unroll
            for (int r = 0; r < 4; r++) {
                int i = ti * 16 + lhi * 4 + r;
                int regi = regbuf[i];
                const float* bi = biasmat + h * 4096 + i * 64 + lrow;
                float sv[4]; float mx = -1e30f;
                #pragma unroll
                for (int tj = 0; tj < 4; tj++) {
                    float v = s[ti][tj][r] + bi[tj * 16];
                    v += (regj[tj] != regi) ? -100.0f : 0.0f;
                    sv[tj] = v; mx = fmaxf(mx, v);
                }
                mx = fmaxf(mx, __shfl_xor(mx, 1));
                mx = fmaxf(mx, __shfl_xor(mx, 2));
                mx = fmaxf(mx, __shfl_xor(mx, 4));
                mx = fmaxf(mx, __shfl_xor(mx, 8));
                float sum = 0.f;
                #pragma unroll
                for (int tj = 0; tj < 4; tj++) {
                    float p = __expf(sv[tj] - mx);
                    s[ti][tj][r] = p; sum += p;
                }
                sum += __shfl_xor(sum, 1);
                sum += __shfl_xor(sum, 2);
                sum += __shfl_xor(sum, 4);
                sum += __shfl_xor(sum, 8);
                rcpv[ti][r] = 1.0f / sum;
            }
        }
        // P -> LDS (bf16, stride 72)
        #pragma unroll
        for (int ti = 0; ti < 4; ti++)
            #pragma unroll
            for (int tj = 0; tj < 4; tj++)
                #pragma unroll
                for (int r = 0; r < 4; r++)
                    pb[(ti * 16 + lhi * 4 + r) * 72 + tj * 16 + lrow] = f2bf(s[ti][tj][r]);
        // PV: out(64x32) = P(64x64) @ V(64x32)
        f32x4 o[4][2];
        #pragma unroll
        for (int i = 0; i < 4; i++) { o[i][0] = zero; o[i][1] = zero; }
        #pragma unroll
        for (int kk = 0; kk < 2; kk++) {
            bf16x8 vf0 = *(const bf16x8*)(vtb + (lrow) * 72 + kk * 32 + lhi * 8);
            bf16x8 vf1 = *(const bf16x8*)(vtb + (16 + lrow) * 72 + kk * 32 + lhi * 8);
            #pragma unroll
            for (int ti = 0; ti < 4; ti++) {
                bf16x8 pf = *(const bf16x8*)(pb + (ti * 16 + lrow) * 72 + kk * 32 + lhi * 8);
                o[ti][0] = __builtin_amdgcn_mfma_f32_16x16x32_bf16(pf, vf0, o[ti][0], 0, 0, 0);
                o[ti][1] = __builtin_amdgcn_mfma_f32_16x16x32_bf16(pf, vf1, o[ti][1], 0, 0, 0);
            }
        }
        // store attn output (global rows), normalize by row sum
        #pragma unroll
        for (int ti = 0; ti < 4; ti++)
            #pragma unroll
            for (int tj = 0; tj < 2; tj++)
                #pragma unroll
                for (int r = 0; r < 4; r++) {
                    float v = o[ti][tj][r] * rcpv[ti][r];
                    attno[(size_t)(gwin * 64 + ti * 16 + lhi * 4 + r) * CDIM + h * 32 + tj * 16 + lrow] = f2bf(v);
                }
    }
}

// ---------------- GEMM2: out = attno @ proj_w + b, window-reverse ----------
__global__ __launch_bounds__(256) void gemm_proj(
    const short* __restrict__ a, const short* __restrict__ wt,
    const float* __restrict__ proj_b, float* __restrict__ out)
{
    __shared__ alignas(16) short Ab[128 * 40];
    __shared__ alignas(16) short Bb[128 * 40];
    int tid = threadIdx.x;
    int bm = blockIdx.x, bn = blockIdx.y;
    int rA = tid >> 1, half = tid & 1;
    const short* asrc = a + (size_t)(bm * 128 + rA) * CDIM + half * 16;
    const short* bsrc = wt + (size_t)(bn * 128 + rA) * CDIM + half * 16;
    short* aw  = &Ab[rA * 40 + half * 16];
    short* bw_ = &Bb[rA * 40 + half * 16];
    int lane = tid & 63, wv = tid >> 6;
    int wr = wv >> 1, wc = wv & 1;
    int lrow = lane & 15, lhi = lane >> 4;
    const short* ard = &Ab[(wr * 64 + lrow) * 40 + lhi * 8];
    const short* brd = &Bb[(wc * 64 + lrow) * 40 + lhi * 8];

    f32x4 zero = {0.f, 0.f, 0.f, 0.f};
    f32x4 acc[4][4];
    #pragma unroll
    for (int i = 0; i < 4; i++)
        #pragma unroll
        for (int j = 0; j < 4; j++) acc[i][j] = zero;

    for (int k0 = 0; k0 < CDIM; k0 += 32) {
        bf16x8 a0 = *(const bf16x8*)(asrc + k0);
        bf16x8 a1 = *(const bf16x8*)(asrc + k0 + 8);
        bf16x8 b0 = *(const bf16x8*)(bsrc + k0);
        bf16x8 b1 = *(const bf16x8*)(bsrc + k0 + 8);
        __syncthreads();
        *(bf16x8*)aw = a0; *(bf16x8*)(aw + 8) = a1;
        *(bf16x8*)bw_ = b0; *(bf16x8*)(bw_ + 8) = b1;
        __syncthreads();
        bf16x8 af[4], bfr[4];
        #pragma unroll
        for (int t = 0; t < 4; t++) af[t]  = *(const bf16x8*)(ard + t * 16 * 40);
        #pragma unroll
        for (int t = 0; t < 4; t++) bfr[t] = *(const bf16x8*)(brd + t * 16 * 40);
        #pragma unroll
        for (int i = 0; i < 4; i++)
            #pragma unroll
            for (int j = 0; j < 4; j++)
                acc[i][j] = __builtin_amdgcn_mfma_f32_16x16x32_bf16(af[i], bfr[j], acc[i][j], 0, 0, 0);
    }
    // epilogue: window reverse + unshift, fp32 out
    #pragma unroll
    for (int ti = 0; ti < 4; ti++) {
        #pragma unroll
        for (int r = 0; r < 4; r++) {
            int m = bm * 128 + wr * 64 + ti * 16 + lhi * 4 + r;
            int b = m >> 12, wIdx = (m >> 6) & 63, tok = m & 63;
            int gh = ((wIdx >> 3) << 3) + (tok >> 3);
            int gw = (wIdx & 7) * 8 + (tok & 7);
            int ih = (gh + SHIFT_) & 63, iw = (gw + SHIFT_) & 63;
            size_t ob = ((size_t)(b << 12) + ih * 64 + iw) * CDIM;
            #pragma unroll
            for (int tj = 0; tj < 4; tj++) {
                int col = bn * 128 + wc * 64 + tj * 16 + lrow;
                out[ob + col] = acc[ti][tj][r] + proj_b[col];
            }
        }
    }
}

extern "C" void kernel_launch(void* const* d_in, const int* in_sizes, int n_in,
                              void* d_out, int out_size, void* d_ws, size_t ws_size,
                              hipStream_t stream) {
    const float* x          = (const float*)d_in[0];
    const float* qkv_w      = (const float*)d_in[1];
    const float* qkv_b      = (const float*)d_in[2];
    const float* proj_w     = (const float*)d_in[3];
    const float* proj_b     = (const float*)d_in[4];
    const float* bias_table = (const float*)d_in[5];
    const int*   rel_index  = (const int*)d_in[6];
    float* out = (float*)d_out;
    char* ws = (char*)d_ws;

    short* qkvwt   = (short*)(ws);                 //  884736 B
    short* projwt  = (short*)(ws + 884736);        //  294912 B
    float* biasmat = (float*)(ws + 1179648);       //  196608 B
    short* qkvbuf  = (short*)(ws + 1376256);       //  75497472 B (one chunk)
    short* attno   = (short*)(ws + 76873728);      //  100663296 B -> total ~169 MB

    prep_kernel<<<1728, 256, 0, stream>>>(qkv_w, proj_w, bias_table, rel_index,
                                          qkvwt, projwt, biasmat);
    for (int c = 0; c < NCHUNK; c++) {
        gemm_qkv<<<dim3(256, 9), 256, 0, stream>>>(x, qkvwt, qkv_b, qkvbuf, c);
        attn_win<<<WINCHUNK, 256, 0, stream>>>(qkvbuf, biasmat, attno, c);
    }
    gemm_proj<<<dim3(1024, 3), 256, 0, stream>>>(attno, projwt, proj_b, out);
}

// Round 2
// 593.213 us; speedup vs baseline: 1.0219x; 1.0219x over previous
//
#include <hip/hip_runtime.h>
#include <hip/hip_bf16.h>

#define CDIM 384
#define NQKV 1152
#define HEADS 12
#define NTOK 64
#define MTOT 131072
#define NCHUNK 4
#define MCHUNK 32768     // rows per chunk (8 images)
#define WINCHUNK 512     // windows per chunk
#define SHIFT_ 4
#define SCALE_Q 0.17677669529663687f  // 32^-0.5

typedef __attribute__((ext_vector_type(8))) short bf16x8;
typedef __attribute__((ext_vector_type(4))) float f32x4;
typedef __attribute__((ext_vector_type(4))) float float4_t;

__device__ inline short f2bf(float f) {
    union { float f; unsigned u; } v; v.f = f;
    unsigned r = v.u + 0x7FFFu + ((v.u >> 16) & 1u);
    return (short)(r >> 16);
}

__device__ inline void gl16(const short* g, const short* l) {
    __builtin_amdgcn_global_load_lds((const __attribute__((address_space(1))) void*)g,
                                     (__attribute__((address_space(3))) void*)l, 16, 0, 0);
}

// inverse of the LDS chunk swizzle X = L ^ ((row(L)&7) at chunk bits 0..2)
// chunk = 16B unit; row = chunk>>2 (64B rows, BK=32 bf16)
__device__ inline int invswz(int c) {
    int b2 = (c >> 2) & 1, b3 = (c >> 3) & 1, b4 = (c >> 4) & 1;
    return (c & ~7) | ((b2 ^ b4) << 2) | (((((c >> 1) & 1)) ^ b3) << 1) | ((c & 1) ^ b2 ^ b4);
}

// ---------------- prep: weight transpose->bf16, bias matrix ----------------
__global__ void prep_kernel(const float* __restrict__ qkv_w,
                            const float* __restrict__ proj_w,
                            const float* __restrict__ bias_table,
                            const int* __restrict__ rel_index,
                            short* __restrict__ qkvwt,
                            short* __restrict__ projwt,
                            float* __restrict__ biasmat) {
    int t = blockIdx.x * 256 + threadIdx.x;
    if (t < NQKV * CDIM) {             // qkvwt[n][k] = qkv_w[k][n]
        int n = t / CDIM, k = t - n * CDIM;
        qkvwt[t] = f2bf(qkv_w[k * NQKV + n]);
    }
    if (t < CDIM * CDIM) {             // projwt[n][k] = proj_w[k][n]
        int n = t / CDIM, k = t - n * CDIM;
        projwt[t] = f2bf(proj_w[k * CDIM + n]);
    }
    if (t < HEADS * NTOK * NTOK) {     // biasmat[h][i][j]
        int h = t >> 12, ij = t & 4095;
        biasmat[t] = bias_table[rel_index[ij] * HEADS + h];
    }
}

// ---------------- xwin: shift + window partition + fp32->bf16 --------------
__global__ __launch_bounds__(256) void xwin_kernel(const float* __restrict__ x,
                                                   short* __restrict__ xw) {
    int t = blockIdx.x * 256 + threadIdx.x;    // one thread = 8 elements
    int mg = t / 48;
    int col = (t - mg * 48) * 8;
    int tok = mg & 63, win = mg >> 6;
    int b = win >> 6, wIdx = win & 63;
    int gh = ((wIdx >> 3) << 3) + (tok >> 3);
    int gw = (wIdx & 7) * 8 + (tok & 7);
    int sh_ = (gh + SHIFT_) & 63, sw_ = (gw + SHIFT_) & 63;
    const float* src = x + (size_t)(b * 4096 + sh_ * 64 + sw_) * CDIM + col;
    float4_t a0 = *(const float4_t*)src;
    float4_t a1 = *(const float4_t*)(src + 4);
    bf16x8 o;
    #pragma unroll
    for (int i = 0; i < 4; i++) { o[i] = f2bf(a0[i]); o[4 + i] = f2bf(a1[i]); }
    *(bf16x8*)(xw + (size_t)t * 8) = o;
}

// ---------------- GEMM1: qkv = xw @ qkv_w^T + b  (bf16 out, m97-style) -----
__global__ __launch_bounds__(256) void gemm_qkv(
    const short* __restrict__ xw, const short* __restrict__ wt,
    const float* __restrict__ qkv_b, short* __restrict__ qkv, int chunk)
{
    __shared__ alignas(16) short As[4096];     // 128 rows x 32 k, swizzled
    __shared__ alignas(16) short Bs[4096];
    __shared__ alignas(16) short Cst[128 * 136];
    int tid = threadIdx.x;
    int hw = blockIdx.x;                       // 2304 blocks, %8==0
    int lb = (hw & 7) * 288 + (hw >> 3);       // XCD-chunked swizzle
    int bm = lb / 9, bn = lb - bm * 9;
    int m0g = chunk * MCHUNK + bm * 128;       // A rows (window-space, chunked)
    int n0 = bn * 128;

    int lane = tid & 63, wv = tid >> 6;
    // staging source chunks (inverse-swizzled so LDS holds swizzled layout)
    int c0 = wv * 128 + lane, c1 = c0 + 64;
    int l0 = invswz(c0), l1 = invswz(c1);
    const short* Ag0 = xw + (size_t)(m0g + (l0 >> 2)) * CDIM + (l0 & 3) * 8;
    const short* Ag1 = xw + (size_t)(m0g + (l1 >> 2)) * CDIM + (l1 & 3) * 8;
    const short* Bg0 = wt + (size_t)(n0 + (l0 >> 2)) * CDIM + (l0 & 3) * 8;
    const short* Bg1 = wt + (size_t)(n0 + (l1 >> 2)) * CDIM + (l1 & 3) * 8;
    const short* Adst0 = (const short*)((const char*)As + wv * 2048);
    const short* Adst1 = (const short*)((const char*)As + wv * 2048 + 1024);
    const short* Bdst0 = (const short*)((const char*)Bs + wv * 2048);
    const short* Bdst1 = (const short*)((const char*)Bs + wv * 2048 + 1024);

    int wr = wv >> 1, wc = wv & 1;
    int lrow = lane & 15, lhi = lane >> 4;
    int arow = wr * 64 + lrow, brow = wc * 64 + lrow;
    const short* ard = As + ((((arow * 64 + lhi * 16)) ^ ((lrow & 7) << 4)) >> 1);
    const short* brd = Bs + ((((brow * 64 + lhi * 16)) ^ ((lrow & 7) << 4)) >> 1);

    f32x4 zero = {0.f, 0.f, 0.f, 0.f};
    f32x4 acc[4][4];
    #pragma unroll
    for (int i = 0; i < 4; i++)
        #pragma unroll
        for (int j = 0; j < 4; j++) acc[i][j] = zero;

    for (int k0 = 0; k0 < CDIM; k0 += 32) {
        gl16(Ag0 + k0, Adst0);
        gl16(Bg0 + k0, Bdst0);
        gl16(Ag1 + k0, Adst1);
        gl16(Bg1 + k0, Bdst1);
        __syncthreads();                       // drains vmcnt
        bf16x8 af[4], bfr[4];
        #pragma unroll
        for (int t = 0; t < 4; t++) af[t]  = *(const bf16x8*)(ard + t * 512);
        #pragma unroll
        for (int t = 0; t < 4; t++) bfr[t] = *(const bf16x8*)(brd + t * 512);
        #pragma unroll
        for (int i = 0; i < 4; i++)
            #pragma unroll
            for (int j = 0; j < 4; j++)
                acc[i][j] = __builtin_amdgcn_mfma_f32_16x16x32_bf16(af[i], bfr[j], acc[i][j], 0, 0, 0);
        __syncthreads();
    }
    // epilogue: +bias, q-scale, LDS transpose, b128 coalesced bf16 stores
    #pragma unroll
    for (int tj = 0; tj < 4; tj++) {
        int col = wc * 64 + tj * 16 + lrow;
        int colg = n0 + col;
        float bias = qkv_b[colg];
        float sc = (colg < CDIM) ? SCALE_Q : 1.0f;
        #pragma unroll
        for (int ti = 0; ti < 4; ti++) {
            int row0 = wr * 64 + ti * 16 + lhi * 4;
            #pragma unroll
            for (int r = 0; r < 4; r++)
                Cst[(row0 + r) * 136 + col] = f2bf((acc[ti][tj][r] + bias) * sc);
        }
    }
    __syncthreads();
    #pragma unroll
    for (int i = 0; i < 8; i++) {
        int rr = i * 16 + (tid >> 4);
        int cc = (tid & 15) * 8;
        bf16x8 v = *(const bf16x8*)(Cst + rr * 136 + cc);
        *(bf16x8*)(qkv + (size_t)(bm * 128 + rr) * NQKV + n0 + cc) = v;   // chunk-local rows
    }
}

// ---------------- attention: one block per window, wave = 3 heads ----------
__global__ __launch_bounds__(256) void attn_win(
    const short* __restrict__ qkv, const float* __restrict__ biasmat,
    short* __restrict__ attno, int chunk)
{
    __shared__ alignas(16) short pbuf[4][64 * 72];
    __shared__ alignas(16) short vtb_s[4][32 * 72];
    __shared__ int regbuf[64];
    int tid = threadIdx.x;
    int wc = blockIdx.x;
    int gwin = chunk * WINCHUNK + wc;
    int wIdx = gwin & 63;
    if (tid < 64) {      // shift-mask region id per token
        int th = tid >> 3, tw = tid & 7;
        int gh = ((wIdx >> 3) << 3) + th;
        int gw = (wIdx & 7) * 8 + tw;
        int rh = gh < 56 ? 0 : (gh < 60 ? 1 : 2);
        int rw = gw < 56 ? 0 : (gw < 60 ? 1 : 2);
        regbuf[tid] = rh * 3 + rw;
    }
    __syncthreads();
    int lane = tid & 63, wv = tid >> 6;
    int lrow = lane & 15, lhi = lane >> 4;
    short* pb  = pbuf[wv];
    short* vtb = vtb_s[wv];
    const short* qb = qkv + (size_t)(wc * 64) * NQKV;   // chunk-local rows
    f32x4 zero = {0.f, 0.f, 0.f, 0.f};

    int regj[4];
    #pragma unroll
    for (int tj = 0; tj < 4; tj++) regj[tj] = regbuf[tj * 16 + lrow];

    for (int hi = 0; hi < 3; hi++) {
        int h = wv * 3 + hi;
        // V rows (token = lane), 32 dims
        const short* vsrc = qb + (size_t)lane * NQKV + 2 * CDIM + h * 32;
        bf16x8 vr0 = *(const bf16x8*)(vsrc);
        bf16x8 vr1 = *(const bf16x8*)(vsrc + 8);
        bf16x8 vr2 = *(const bf16x8*)(vsrc + 16);
        bf16x8 vr3 = *(const bf16x8*)(vsrc + 24);
        // Q/K fragments (q pre-scaled in GEMM1)
        bf16x8 qf[4], kf[4];
        #pragma unroll
        for (int t = 0; t < 4; t++) {
            qf[t] = *(const bf16x8*)(qb + (size_t)(t * 16 + lrow) * NQKV + h * 32 + lhi * 8);
            kf[t] = *(const bf16x8*)(qb + (size_t)(t * 16 + lrow) * NQKV + CDIM + h * 32 + lhi * 8);
        }
        f32x4 s[4][4];
        #pragma unroll
        for (int i = 0; i < 4; i++)
            #pragma unroll
            for (int j = 0; j < 4; j++)
                s[i][j] = __builtin_amdgcn_mfma_f32_16x16x32_bf16(qf[i], kf[j], zero, 0, 0, 0);
        // stage V^T in LDS (pad 64->72 tokens: conflict-free b128 reads)
        #pragma unroll
        for (int d = 0; d < 8; d++) {
            vtb[d * 72 + lane]        = vr0[d];
            vtb[(d + 8) * 72 + lane]  = vr1[d];
            vtb[(d + 16) * 72 + lane] = vr2[d];
            vtb[(d + 24) * 72 + lane] = vr3[d];
        }
        // softmax (rows split: 16 lanes x 4 tj hold one row)
        float rcpv[4][4];
        #pragma unroll
        for (int ti = 0; ti < 4; ti++) {
            #pragma unroll
            for (int r = 0; r < 4; r++) {
                int i = ti * 16 + lhi * 4 + r;
                int regi = regbuf[i];
                const float* bi = biasmat + h * 4096 + i * 64 + lrow;
                float sv[4]; float mx = -1e30f;
                #pragma unroll
                for (int tj = 0; tj < 4; tj++) {
                    float v = s[ti][tj][r] + bi[tj * 16];
                    v += (regj[tj] != regi) ? -100.0f : 0.0f;
                    sv[tj] = v; mx = fmaxf(mx, v);
                }
                mx = fmaxf(mx, __shfl_xor(mx, 1));
                mx = fmaxf(mx, __shfl_xor(mx, 2));
                mx = fmaxf(mx, __shfl_xor(mx, 4));
                mx = fmaxf(mx, __shfl_xor(mx, 8));
                float sum = 0.f;
                #pragma unroll
                for (int tj = 0; tj < 4; tj++) {
                    float p = __expf(sv[tj] - mx);
                    s[ti][tj][r] = p; sum += p;
                }
                sum += __shfl_xor(sum, 1);
                sum += __shfl_xor(sum, 2);
                sum += __shfl_xor(sum, 4);
                sum += __shfl_xor(sum, 8);
                rcpv[ti][r] = 1.0f / sum;
            }
        }
        // P -> LDS (bf16, stride 72)
        #pragma unroll
        for (int ti = 0; ti < 4; ti++)
            #pragma unroll
            for (int tj = 0; tj < 4; tj++)
                #pragma unroll
                for (int r = 0; r < 4; r++)
                    pb[(ti * 16 + lhi * 4 + r) * 72 + tj * 16 + lrow] = f2bf(s[ti][tj][r]);
        // PV: out(64x32) = P(64x64) @ V(64x32)
        f32x4 o[4][2];
        #pragma unroll
        for (int i = 0; i < 4; i++) { o[i][0] = zero; o[i][1] = zero; }
        #pragma unroll
        for (int kk = 0; kk < 2; kk++) {
            bf16x8 vf0 = *(const bf16x8*)(vtb + (lrow) * 72 + kk * 32 + lhi * 8);
            bf16x8 vf1 = *(const bf16x8*)(vtb + (16 + lrow) * 72 + kk * 32 + lhi * 8);
            #pragma unroll
            for (int ti = 0; ti < 4; ti++) {
                bf16x8 pf = *(const bf16x8*)(pb + (ti * 16 + lrow) * 72 + kk * 32 + lhi * 8);
                o[ti][0] = __builtin_amdgcn_mfma_f32_16x16x32_bf16(pf, vf0, o[ti][0], 0, 0, 0);
                o[ti][1] = __builtin_amdgcn_mfma_f32_16x16x32_bf16(pf, vf1, o[ti][1], 0, 0, 0);
            }
        }
        // store attn output (global rows), normalize by row sum
        #pragma unroll
        for (int ti = 0; ti < 4; ti++)
            #pragma unroll
            for (int tj = 0; tj < 2; tj++)
                #pragma unroll
                for (int r = 0; r < 4; r++) {
                    float v = o[ti][tj][r] * rcpv[ti][r];
                    attno[(size_t)(gwin * 64 + ti * 16 + lhi * 4 + r) * CDIM + h * 32 + tj * 16 + lrow] = f2bf(v);
                }
    }
}

// ---------------- GEMM2: out = attno @ proj_w^T + b, window-reverse --------
__global__ __launch_bounds__(256) void gemm_proj(
    const short* __restrict__ a, const short* __restrict__ wt,
    const float* __restrict__ proj_b, float* __restrict__ out)
{
    __shared__ alignas(16) short As[4096];
    __shared__ alignas(16) short Bs[4096];
    int tid = threadIdx.x;
    int hw = blockIdx.x;                       // 3072 blocks, %8==0
    int lb = (hw & 7) * 384 + (hw >> 3);
    int bm = lb / 3, bn = lb - bm * 3;
    int m0 = bm * 128, n0 = bn * 128;

    int lane = tid & 63, wv = tid >> 6;
    int c0 = wv * 128 + lane, c1 = c0 + 64;
    int l0 = invswz(c0), l1 = invswz(c1);
    const short* Ag0 = a + (size_t)(m0 + (l0 >> 2)) * CDIM + (l0 & 3) * 8;
    const short* Ag1 = a + (size_t)(m0 + (l1 >> 2)) * CDIM + (l1 & 3) * 8;
    const short* Bg0 = wt + (size_t)(n0 + (l0 >> 2)) * CDIM + (l0 & 3) * 8;
    const short* Bg1 = wt + (size_t)(n0 + (l1 >> 2)) * CDIM + (l1 & 3) * 8;
    const short* Adst0 = (const short*)((const char*)As + wv * 2048);
    const short* Adst1 = (const short*)((const char*)As + wv * 2048 + 1024);
    const short* Bdst0 = (const short*)((const char*)Bs + wv * 2048);
    const short* Bdst1 = (const short*)((const char*)Bs + wv * 2048 + 1024);

    int wr = wv >> 1, wc = wv & 1;
    int lrow = lane & 15, lhi = lane >> 4;
    int arow = wr * 64 + lrow, brow = wc * 64 + lrow;
    const short* ard = As + ((((arow * 64 + lhi * 16)) ^ ((lrow & 7) << 4)) >> 1);
    const short* brd = Bs + ((((brow * 64 + lhi * 16)) ^ ((lrow & 7) << 4)) >> 1);

    f32x4 zero = {0.f, 0.f, 0.f, 0.f};
    f32x4 acc[4][4];
    #pragma unroll
    for (int i = 0; i < 4; i++)
        #pragma unroll
        for (int j = 0; j < 4; j++) acc[i][j] = zero;

    for (int k0 = 0; k0 < CDIM; k0 += 32) {
        gl16(Ag0 + k0, Adst0);
        gl16(Bg0 + k0, Bdst0);
        gl16(Ag1 + k0, Adst1);
        gl16(Bg1 + k0, Bdst1);
        __syncthreads();
        bf16x8 af[4], bfr[4];
        #pragma unroll
        for (int t = 0; t < 4; t++) af[t]  = *(const bf16x8*)(ard + t * 512);
        #pragma unroll
        for (int t = 0; t < 4; t++) bfr[t] = *(const bf16x8*)(brd + t * 512);
        #pragma unroll
        for (int i = 0; i < 4; i++)
            #pragma unroll
            for (int j = 0; j < 4; j++)
                acc[i][j] = __builtin_amdgcn_mfma_f32_16x16x32_bf16(af[i], bfr[j], acc[i][j], 0, 0, 0);
        __syncthreads();
    }
    // epilogue: window reverse + unshift, fp32 out
    #pragma unroll
    for (int ti = 0; ti < 4; ti++) {
        #pragma unroll
        for (int r = 0; r < 4; r++) {
            int m = m0 + wr * 64 + ti * 16 + lhi * 4 + r;
            int b = m >> 12, wIdx = (m >> 6) & 63, tok = m & 63;
            int gh = ((wIdx >> 3) << 3) + (tok >> 3);
            int gw = (wIdx & 7) * 8 + (tok & 7);
            int ih = (gh + SHIFT_) & 63, iw = (gw + SHIFT_) & 63;
            size_t ob = ((size_t)(b << 12) + ih * 64 + iw) * CDIM;
            #pragma unroll
            for (int tj = 0; tj < 4; tj++) {
                int col = n0 + wc * 64 + tj * 16 + lrow;
                out[ob + col] = acc[ti][tj][r] + proj_b[col];
            }
        }
    }
}

extern "C" void kernel_launch(void* const* d_in, const int* in_sizes, int n_in,
                              void* d_out, int out_size, void* d_ws, size_t ws_size,
                              hipStream_t stream) {
    const float* x          = (const float*)d_in[0];
    const float* qkv_w      = (const float*)d_in[1];
    const float* qkv_b      = (const float*)d_in[2];
    const float* proj_w     = (const float*)d_in[3];
    const float* proj_b     = (const float*)d_in[4];
    const float* bias_table = (const float*)d_in[5];
    const int*   rel_index  = (const int*)d_in[6];
    float* out = (float*)d_out;
    char* ws = (char*)d_ws;

    short* qkvwt   = (short*)(ws);                   //  884736 B
    short* projwt  = (short*)(ws + 884736);          //  294912 B
    float* biasmat = (float*)(ws + 1179648);         //  196608 B
    short* xw      = (short*)(ws + 1376256);         //  100663296 B
    short* qkvbuf  = (short*)(ws + 102039552);       //  75497472 B (one chunk)
    short* attno   = (short*)(ws + 177537024);       //  100663296 B -> total ~265 MB

    prep_kernel<<<1728, 256, 0, stream>>>(qkv_w, proj_w, bias_table, rel_index,
                                          qkvwt, projwt, biasmat);
    xwin_kernel<<<24576, 256, 0, stream>>>(x, xw);
    for (int c = 0; c < NCHUNK; c++) {
        gemm_qkv<<<2304, 256, 0, stream>>>(xw, qkvwt, qkv_b, qkvbuf, c);
        attn_win<<<WINCHUNK, 256, 0, stream>>>(qkvbuf, biasmat, attno, c);
    }
    gemm_proj<<<3072, 256, 0, stream>>>(attno, projwt, proj_b, out);
}

// Round 3
// 535.103 us; speedup vs baseline: 1.1329x; 1.1086x over previous
//
#include <hip/hip_runtime.h>
#include <hip/hip_bf16.h>

#define CDIM 384
#define NQKV 1152
#define HEADS 12
#define SHIFT_ 4
#define SCALE_Q 0.17677669529663687f  // 32^-0.5

typedef __attribute__((ext_vector_type(8))) short bf16x8;
typedef __attribute__((ext_vector_type(4))) float f32x4;
typedef __attribute__((ext_vector_type(4))) float float4_t;

__device__ inline short f2bf(float f) {
    union { float f; unsigned u; } v; v.f = f;
    unsigned r = v.u + 0x7FFFu + ((v.u >> 16) & 1u);
    return (short)(r >> 16);
}

// ---------------- prep: weight transpose->bf16, bias matrix ----------------
__global__ void prep_kernel(const float* __restrict__ qkv_w,
                            const float* __restrict__ proj_w,
                            const float* __restrict__ bias_table,
                            const int* __restrict__ rel_index,
                            short* __restrict__ qkvwt,
                            short* __restrict__ projwt,
                            float* __restrict__ biasmat) {
    int t = blockIdx.x * 256 + threadIdx.x;
    if (t < NQKV * CDIM) {             // qkvwt[n][k] = qkv_w[k][n]
        int n = t / CDIM, k = t - n * CDIM;
        qkvwt[t] = f2bf(qkv_w[k * NQKV + n]);
    }
    if (t < CDIM * CDIM) {             // projwt[n][k] = proj_w[k][n]
        int n = t / CDIM, k = t - n * CDIM;
        projwt[t] = f2bf(proj_w[k * CDIM + n]);
    }
    if (t < HEADS * 64 * 64) {         // biasmat[h][i][j]
        int h = t >> 12, ij = t & 4095;
        biasmat[t] = bias_table[rel_index[ij] * HEADS + h];
    }
}

// ---------------- fully fused: x -> qkv -> attention -> proj -> out --------
// one block (256 thr, 4 waves) per window; wave = 3 heads.
// LDS: Xs [64][384] bf16 swizzled (49152) | per-wave scratch 4x14848
//      attno [64][384] bf16 swizzled (49152) | regbuf (256)  => 157952 B
__global__ __launch_bounds__(256, 1) void fused_swin(
    const float* __restrict__ x, const short* __restrict__ qkvwt,
    const float* __restrict__ qkv_b, const short* __restrict__ projwt,
    const float* __restrict__ proj_b, const float* __restrict__ biasmat,
    float* __restrict__ out)
{
    __shared__ __attribute__((aligned(16))) char smem[157952];
    char* xs = smem;                                  // Xs, swizzled rows of 768B
    int tid = threadIdx.x;
    int lane = tid & 63, wv = tid >> 6;
    int lrow = lane & 15, lhi = lane >> 4;
    char* pw  = smem + 49152 + wv * 14848;            // per-wave scratch
    char* qkb = pw;                                   // Q[64][40]s @0, K @+5120 ; P overlays [0,9216)
    char* kkb = pw + 5120;
    char* vtb = pw + 10240;                           // Vt [32][72] shorts
    char* an  = smem + 49152 + 59392;                 // attno, swizzled rows of 768B
    int* regbuf = (int*)(smem + 157696);

    int w = blockIdx.x;
    int b = w >> 6, wIdx = w & 63;

    // ---- region ids for shift mask ----
    if (tid < 64) {
        int gh = ((wIdx >> 3) << 3) + (tid >> 3);
        int gw = (wIdx & 7) * 8 + (tid & 7);
        int rh = gh < 56 ? 0 : (gh < 60 ? 1 : 2);
        int rw = gw < 56 ? 0 : (gw < 60 ? 1 : 2);
        regbuf[tid] = rh * 3 + rw;
    }

    // ---- stage x window -> Xs (bf16, XOR-swizzled) ----
    #pragma unroll
    for (int it = 0; it < 6; it++) {
        int c = it * 256 + tid;                       // 1536 chunks of 16 elems
        int tok = c / 24, kc = (c - tok * 24) * 16;
        int gh = ((wIdx >> 3) << 3) + (tok >> 3);
        int gw = (wIdx & 7) * 8 + (tok & 7);
        int sh_ = (gh + SHIFT_) & 63, sw_ = (gw + SHIFT_) & 63;
        const float* src = x + (size_t)(b * 4096 + sh_ * 64 + sw_) * CDIM + kc;
        float4_t a0 = *(const float4_t*)(src);
        float4_t a1 = *(const float4_t*)(src + 4);
        float4_t a2 = *(const float4_t*)(src + 8);
        float4_t a3 = *(const float4_t*)(src + 12);
        bf16x8 w0, w1;
        #pragma unroll
        for (int i = 0; i < 4; i++) {
            w0[i] = f2bf(a0[i]); w0[4 + i] = f2bf(a1[i]);
            w1[i] = f2bf(a2[i]); w1[4 + i] = f2bf(a3[i]);
        }
        int base = tok * 768 + kc * 2, sw = (tok & 7) << 4;
        *(bf16x8*)(xs + (base ^ sw)) = w0;
        *(bf16x8*)(xs + ((base + 16) ^ sw)) = w1;
    }
    __syncthreads();

    f32x4 zero = {0.f, 0.f, 0.f, 0.f};
    int regj[4], regi_[4][4];
    #pragma unroll
    for (int tj = 0; tj < 4; tj++) regj[tj] = regbuf[tj * 16 + lrow];
    #pragma unroll
    for (int ti = 0; ti < 4; ti++)
        #pragma unroll
        for (int r = 0; r < 4; r++) regi_[ti][r] = regbuf[ti * 16 + lhi * 4 + r];

    int aswz = (lrow & 7) << 4;                       // Xs/attno read swizzle

    for (int hi = 0; hi < 3; hi++) {
        int h = wv * 3 + hi;
        // ---- qkv GEMM for this head: out 64 x (32q|32k|32v), K=384 ----
        f32x4 acc[4][6];
        #pragma unroll
        for (int i = 0; i < 4; i++)
            #pragma unroll
            for (int j = 0; j < 6; j++) acc[i][j] = zero;
        // B row bases: ct -> part (0=q,1=k,2=v), sub 16-row half
        const short* brow[6];
        #pragma unroll
        for (int ct = 0; ct < 6; ct++) {
            int part = ct >> 1, sub = ct & 1;
            brow[ct] = qkvwt + (size_t)(part * CDIM + h * 32 + sub * 16 + lrow) * CDIM + lhi * 8;
        }
        for (int ks = 0; ks < 12; ks++) {
            bf16x8 bf[6];
            #pragma unroll
            for (int ct = 0; ct < 6; ct++) bf[ct] = *(const bf16x8*)(brow[ct] + ks * 32);
            bf16x8 af[4];
            #pragma unroll
            for (int rt = 0; rt < 4; rt++)
                af[rt] = *(const bf16x8*)(xs + (((rt * 16 + lrow) * 768 + ks * 64 + lhi * 16) ^ aswz));
            #pragma unroll
            for (int rt = 0; rt < 4; rt++)
                #pragma unroll
                for (int ct = 0; ct < 6; ct++)
                    acc[rt][ct] = __builtin_amdgcn_mfma_f32_16x16x32_bf16(af[rt], bf[ct], acc[rt][ct], 0, 0, 0);
        }
        // ---- epilogue: +bias, q-scale; scatter Q,K,Vt to per-wave LDS ----
        #pragma unroll
        for (int ct = 0; ct < 6; ct++) {
            int part = ct >> 1, sub = ct & 1;
            int d = sub * 16 + lrow;                  // 0..31 within part
            float bias = qkv_b[part * CDIM + h * 32 + d];
            #pragma unroll
            for (int rt = 0; rt < 4; rt++)
                #pragma unroll
                for (int r = 0; r < 4; r++) {
                    int token = rt * 16 + lhi * 4 + r;
                    float v = acc[rt][ct][r] + bias;
                    if (part == 0)
                        *(short*)(qkb + token * 80 + d * 2) = f2bf(v * SCALE_Q);
                    else if (part == 1)
                        *(short*)(kkb + token * 80 + d * 2) = f2bf(v);
                    else
                        *(short*)(vtb + (d * 72 + token) * 2) = f2bf(v);
                }
        }
        // ---- S = Q K^T (per-wave private; in-wave LDS ordering is safe) ----
        bf16x8 qf[4], kf[4];
        #pragma unroll
        for (int t = 0; t < 4; t++) {
            qf[t] = *(const bf16x8*)(qkb + (t * 16 + lrow) * 80 + lhi * 16);
            kf[t] = *(const bf16x8*)(kkb + (t * 16 + lrow) * 80 + lhi * 16);
        }
        f32x4 s[4][4];
        #pragma unroll
        for (int i = 0; i < 4; i++)
            #pragma unroll
            for (int j = 0; j < 4; j++)
                s[i][j] = __builtin_amdgcn_mfma_f32_16x16x32_bf16(qf[i], kf[j], zero, 0, 0, 0);
        // ---- softmax rows (16-lane groups), bias + shift mask ----
        float rcpv[4][4];
        #pragma unroll
        for (int ti = 0; ti < 4; ti++) {
            #pragma unroll
            for (int r = 0; r < 4; r++) {
                int i = ti * 16 + lhi * 4 + r;
                int regi = regi_[ti][r];
                const float* bi = biasmat + h * 4096 + i * 64 + lrow;
                float sv[4]; float mx = -1e30f;
                #pragma unroll
                for (int tj = 0; tj < 4; tj++) {
                    float v = s[ti][tj][r] + bi[tj * 16];
                    v += (regj[tj] != regi) ? -100.0f : 0.0f;
                    sv[tj] = v; mx = fmaxf(mx, v);
                }
                mx = fmaxf(mx, __shfl_xor(mx, 1));
                mx = fmaxf(mx, __shfl_xor(mx, 2));
                mx = fmaxf(mx, __shfl_xor(mx, 4));
                mx = fmaxf(mx, __shfl_xor(mx, 8));
                float sum = 0.f;
                #pragma unroll
                for (int tj = 0; tj < 4; tj++) {
                    float p = __expf(sv[tj] - mx);
                    s[ti][tj][r] = p; sum += p;
                }
                sum += __shfl_xor(sum, 1);
                sum += __shfl_xor(sum, 2);
                sum += __shfl_xor(sum, 4);
                sum += __shfl_xor(sum, 8);
                rcpv[ti][r] = 1.0f / sum;
            }
        }
        // ---- P -> LDS (overlays Q/K region; frags already in regs) ----
        #pragma unroll
        for (int ti = 0; ti < 4; ti++)
            #pragma unroll
            for (int tj = 0; tj < 4; tj++)
                #pragma unroll
                for (int r = 0; r < 4; r++)
                    *(short*)(qkb + ((ti * 16 + lhi * 4 + r) * 72 + tj * 16 + lrow) * 2) = f2bf(s[ti][tj][r]);
        // ---- PV: out(64x32) = P(64x64) @ V(64x32) ----
        f32x4 o[4][2];
        #pragma unroll
        for (int i = 0; i < 4; i++) { o[i][0] = zero; o[i][1] = zero; }
        #pragma unroll
        for (int kk = 0; kk < 2; kk++) {
            bf16x8 vf0 = *(const bf16x8*)(vtb + (lrow * 72 + kk * 32 + lhi * 8) * 2);
            bf16x8 vf1 = *(const bf16x8*)(vtb + ((16 + lrow) * 72 + kk * 32 + lhi * 8) * 2);
            #pragma unroll
            for (int ti = 0; ti < 4; ti++) {
                bf16x8 pf = *(const bf16x8*)(qkb + ((ti * 16 + lrow) * 72 + kk * 32 + lhi * 8) * 2);
                o[ti][0] = __builtin_amdgcn_mfma_f32_16x16x32_bf16(pf, vf0, o[ti][0], 0, 0, 0);
                o[ti][1] = __builtin_amdgcn_mfma_f32_16x16x32_bf16(pf, vf1, o[ti][1], 0, 0, 0);
            }
        }
        // ---- out_h -> attno LDS (swizzled), normalized ----
        #pragma unroll
        for (int ti = 0; ti < 4; ti++)
            #pragma unroll
            for (int tj = 0; tj < 2; tj++)
                #pragma unroll
                for (int r = 0; r < 4; r++) {
                    int token = ti * 16 + lhi * 4 + r;
                    int col = h * 32 + tj * 16 + lrow;
                    int byte = (token * 768 + col * 2) ^ ((token & 7) << 4);
                    *(short*)(an + byte) = f2bf(o[ti][tj][r] * rcpv[ti][r]);
                }
    }
    __syncthreads();   // all heads' attno written

    // ---- proj GEMM: out = attno @ proj_w^T + b; wave = 96 out cols ----
    {
        f32x4 acc[4][6];
        #pragma unroll
        for (int i = 0; i < 4; i++)
            #pragma unroll
            for (int j = 0; j < 6; j++) acc[i][j] = zero;
        const short* brow[6];
        #pragma unroll
        for (int ct = 0; ct < 6; ct++)
            brow[ct] = projwt + (size_t)(wv * 96 + ct * 16 + lrow) * CDIM + lhi * 8;
        for (int ks = 0; ks < 12; ks++) {
            bf16x8 bf[6];
            #pragma unroll
            for (int ct = 0; ct < 6; ct++) bf[ct] = *(const bf16x8*)(brow[ct] + ks * 32);
            bf16x8 af[4];
            #pragma unroll
            for (int rt = 0; rt < 4; rt++)
                af[rt] = *(const bf16x8*)(an + (((rt * 16 + lrow) * 768 + ks * 64 + lhi * 16) ^ aswz));
            #pragma unroll
            for (int rt = 0; rt < 4; rt++)
                #pragma unroll
                for (int ct = 0; ct < 6; ct++)
                    acc[rt][ct] = __builtin_amdgcn_mfma_f32_16x16x32_bf16(af[rt], bf[ct], acc[rt][ct], 0, 0, 0);
        }
        // epilogue: +proj_b, window-reverse + unshift scatter, fp32
        #pragma unroll
        for (int rt = 0; rt < 4; rt++)
            #pragma unroll
            for (int r = 0; r < 4; r++) {
                int token = rt * 16 + lhi * 4 + r;
                int gh = ((wIdx >> 3) << 3) + (token >> 3);
                int gw = (wIdx & 7) * 8 + (token & 7);
                int ih = (gh + SHIFT_) & 63, iw = (gw + SHIFT_) & 63;
                float* orow = out + (size_t)(b * 4096 + ih * 64 + iw) * CDIM;
                #pragma unroll
                for (int ct = 0; ct < 6; ct++) {
                    int col = wv * 96 + ct * 16 + lrow;
                    orow[col] = acc[rt][ct][r] + proj_b[col];
                }
            }
    }
}

extern "C" void kernel_launch(void* const* d_in, const int* in_sizes, int n_in,
                              void* d_out, int out_size, void* d_ws, size_t ws_size,
                              hipStream_t stream) {
    const float* x          = (const float*)d_in[0];
    const float* qkv_w      = (const float*)d_in[1];
    const float* qkv_b      = (const float*)d_in[2];
    const float* proj_w     = (const float*)d_in[3];
    const float* proj_b     = (const float*)d_in[4];
    const float* bias_table = (const float*)d_in[5];
    const int*   rel_index  = (const int*)d_in[6];
    float* out = (float*)d_out;
    char* ws = (char*)d_ws;

    short* qkvwt   = (short*)(ws);                 //  884736 B
    short* projwt  = (short*)(ws + 884736);        //  294912 B
    float* biasmat = (float*)(ws + 1179648);       //  786432 B  (~2 MB total)

    prep_kernel<<<1728, 256, 0, stream>>>(qkv_w, proj_w, bias_table, rel_index,
                                          qkvwt, projwt, biasmat);
    fused_swin<<<2048, 256, 0, stream>>>(x, qkvwt, qkv_b, projwt, proj_b,
                                         biasmat, out);
}